// Round 3
// baseline (920.922 us; speedup 1.0000x reference)
//
#include <hip/hip_runtime.h>
#include <stdint.h>

// Problem constants (fixed by setup_inputs): B=2, C=32, H=W=D=96, N=30000
#define HWD 884736ull          // 96*96*96
#define NV 30000               // vertices per batch
#define AST 1032               // LDS A-tile row stride (shorts); +8 pad breaks pow2 strides

typedef __attribute__((ext_vector_type(8))) __bf16 bf16x8;
typedef __attribute__((ext_vector_type(4))) float f32x4;
typedef __attribute__((ext_vector_type(2))) float f32x2;
typedef __attribute__((ext_vector_type(4))) unsigned int uint4v;

__device__ __forceinline__ unsigned short f2bf(float f) {
    union { float f; unsigned int u; } v; v.f = f;
    unsigned int u = v.u;
    return (unsigned short)((u + 0x7FFFu + ((u >> 16) & 1u)) >> 16);  // RNE
}

// unpack 2 packed bf16 (channels c0, c0+1) -> 2 floats
__device__ __forceinline__ f32x2 up2(unsigned int u) {
    union { unsigned int u; float f; } lo, hi;
    lo.u = u << 16;
    hi.u = u & 0xffff0000u;
    f32x2 r = {lo.f, hi.f};
    return r;
}

__device__ __forceinline__ f32x2 fma2s(f32x2 x, float s, f32x2 acc) {
    acc[0] = fmaf(x[0], s, acc[0]);
    acc[1] = fmaf(x[1], s, acc[1]);
    return acc;
}

// Per-axis: replicate reference clamp/floor math for shifts {-1,0,1}, then fold
// into 4-wide window weights. Window start ws = clamp(x0_center-1, 0, 92).
__device__ __forceinline__ void axis_setup(float coord, float sc, int& wstart, float w[3][4]) {
    int i0[3], i1[3];
    float fr[3];
#pragma unroll
    for (int a = 0; a < 3; ++a) {
        float g = coord + (float)(a - 1) * sc;
        float ix = (g + 1.0f) * 0.5f * 95.0f;
        ix = fminf(fmaxf(ix, 0.0f), 95.0f);
        float fl = floorf(ix);
        int x0 = (int)fl;
        i0[a] = x0;
        i1[a] = min(x0 + 1, 95);
        fr[a] = ix - fl;
    }
    int ws = min(max(i0[1] - 1, 0), 92);
    wstart = ws;
#pragma unroll
    for (int a = 0; a < 3; ++a) {
        int d0 = min(max(i0[a] - ws, 0), 3);
        int d1 = min(max(i1[a] - ws, 0), 3);
        float f1 = fr[a], f0 = 1.0f - f1;
#pragma unroll
        for (int j = 0; j < 4; ++j)
            w[a][j] = (d0 == j ? f0 : 0.0f) + (d1 == j ? f1 : 0.0f);
    }
}

// Pack conv_w (32,32,1,27) fp32 -> bf16 B-fragments for mfma_f32_16x16x32_bf16.
// element j of wp[(s*2+t)*64 + lane] is B[k = s*32 + (lane>>4)*8 + j][o = t*16 + (lane&15)]
__global__ __launch_bounds__(256) void prep_kernel(const float* __restrict__ cw,
                                                   unsigned short* __restrict__ Wp) {
    int gid = blockIdx.x * 256 + threadIdx.x;  // 0..32767
    int j = gid & 7;
    int l = (gid >> 3) & 63;
    int t = (gid >> 9) & 1;
    int s = gid >> 10;
    int kk = ((l >> 4) & 3) * 8 + j;
    int o = t * 16 + (l & 15);
    float v = 0.0f;
    if (kk < 27) v = cw[(size_t)o * 864 + s * 27 + kk];
    Wp[gid] = f2bf(v);
}

// (B,C,H,W,D) fp32 -> (B,H,W,D,C) bf16. One block per (b,z,y) row: 96 x * 32 c.
__global__ __launch_bounds__(256) void transpose_kernel(const float* __restrict__ vox,
                                                        unsigned short* __restrict__ voxT) {
    int blk = blockIdx.x;            // 0..18431 encodes (b, z, y)
    int tid = threadIdx.x;
    int b = blk / 9216;
    int zy = blk % 9216;
    const float* src = vox + (size_t)b * 32 * HWD + (size_t)zy * 96;
    unsigned short* dst = voxT + (size_t)blk * 3072;
#pragma unroll
    for (int i = 0; i < 3; ++i) {
        int idx = i * 256 + tid;     // 0..767
        int c = idx & 31;
        int x4 = idx >> 5;           // 0..23
        f32x4 v = *(const f32x4*)(src + (size_t)c * HWD + x4 * 4);
#pragma unroll
        for (int k = 0; k < 4; ++k)
            dst[(x4 * 4 + k) * 32 + c] = f2bf(v[k]);
    }
}

// Fused sample + GEMM. Block = 256 threads = 16 vertices x 16 channel-pairs.
// Each thread gathers its vertex's 4x4x4 window for 2 packed channels (uint
// loads: 16 lanes x 4B = one 64B line per voxel), does the separable
// x->y->z contraction for both channels (float2 math), writes bf16 rows into
// the LDS A-tile in XOR-swizzled 16B units (kills the 16-way write-bank
// serialization of the natural layout). Waves 0/1 then run the 16x1024 @
// 1024x32 MFMA GEMM (n-half = wave id), un-swizzling A-unit addresses.
__global__ __launch_bounds__(256, 4) void fused_kernel(const unsigned short* __restrict__ voxT,
                                                       const float* __restrict__ verts,
                                                       const unsigned short* __restrict__ Wp,
                                                       const float* __restrict__ bias,
                                                       float* __restrict__ out) {
    __shared__ __align__(16) unsigned short At[16 * AST];
    int tid = threadIdx.x;
    int vl = tid >> 4;               // vertex-in-block 0..15
    int cp = tid & 15;               // channel pair 0..15 -> channels 2cp, 2cp+1
    int c0 = cp * 2;
    int vg = (int)blockIdx.x * 16 + vl;   // 3750*16 = 60000 exactly

    const float* vp = verts + (size_t)vg * 3;
    float vx = vp[0], vy = vp[1], vz = vp[2];
    const float sc = 2.0f / 95.0f;
    int wsx, wsy, wsz;
    float wx[3][4], wy[3][4], wz[3][4];
    axis_setup(vx, sc, wsx, wx);  // x -> D axis (innermost spatial)
    axis_setup(vy, sc, wsy, wy);  // y -> W axis
    axis_setup(vz, sc, wsz, wz);  // z -> H axis
    int bb = (vg >= NV) ? 1 : 0;
    const unsigned short* vb = voxT + (size_t)bb * HWD * 32 + c0;

    f32x2 f2[27];
#pragma unroll
    for (int k = 0; k < 27; ++k) f2[k] = (f32x2){0.0f, 0.0f};

#pragma unroll
    for (int tz = 0; tz < 4; ++tz) {
        f32x2 ry[9];
#pragma unroll
        for (int i = 0; i < 9; ++i) ry[i] = (f32x2){0.0f, 0.0f};
#pragma unroll
        for (int ty = 0; ty < 4; ++ty) {
            const unsigned int* row = (const unsigned int*)(
                vb + (((size_t)(wsz + tz) * 96 + (size_t)(wsy + ty)) * 96 + wsx) * 32);
            unsigned int u0 = row[0], u1 = row[16], u2 = row[32], u3 = row[48];
            f32x2 b0 = up2(u0), b1 = up2(u1), b2 = up2(u2), b3 = up2(u3);
#pragma unroll
            for (int a = 0; a < 3; ++a) {
                f32x2 rxt = (f32x2){0.0f, 0.0f};
                rxt = fma2s(b0, wx[a][0], rxt);
                rxt = fma2s(b1, wx[a][1], rxt);
                rxt = fma2s(b2, wx[a][2], rxt);
                rxt = fma2s(b3, wx[a][3], rxt);
#pragma unroll
                for (int b = 0; b < 3; ++b)
                    ry[3 * b + a] = fma2s(rxt, wy[b][ty], ry[3 * b + a]);
            }
        }
#pragma unroll
        for (int g = 0; g < 3; ++g)
#pragma unroll
            for (int b = 0; b < 3; ++b)
#pragma unroll
                for (int a = 0; a < 3; ++a)
                    f2[9 * a + 3 * b + g] = fma2s(ry[3 * b + a], wz[g][tz], f2[9 * a + 3 * b + g]);
    }

    // Pack both channels' 27+5pad taps into 8 16B units; store unit j at
    // swizzled slot j^rot (rot=cp&7) -> per-store bank groups span all 8.
    unsigned short* basep = &At[vl * AST + cp * 64];
    int rot = cp & 7;
#pragma unroll
    for (int j = 0; j < 8; ++j) {
        const int ch = j >> 2;           // 0 -> channel c0, 1 -> c0+1
        const int kb = (j & 3) * 8;      // tap base within the channel's 32-slot block
        unsigned int pw[4];
#pragma unroll
        for (int t2 = 0; t2 < 4; ++t2) {
            int k0 = kb + 2 * t2, k1 = k0 + 1;
            float lo = (k0 < 27) ? f2[k0][ch] : 0.0f;
            float hi = (k1 < 27) ? f2[k1][ch] : 0.0f;
            pw[t2] = (unsigned int)f2bf(lo) | ((unsigned int)f2bf(hi) << 16);
        }
        uint4v s = {pw[0], pw[1], pw[2], pw[3]};
        *(uint4v*)(basep + (j ^ rot) * 8) = s;
    }

    __syncthreads();

    int wv = tid >> 6;               // wave id 0..3; waves 0,1 do the GEMM
    if (wv < 2) {
        int lane = tid & 63;
        int mrow = lane & 15, quad = lane >> 4;
        const bf16x8* wp = (const bf16x8*)Wp;
        f32x4 acc = {0.f, 0.f, 0.f, 0.f};
#pragma unroll 8
        for (int s = 0; s < 32; ++s) {
            int u = s * 4 + quad;                 // logical 16B unit
            int p = u ^ ((u >> 3) & 7);           // un-swizzle
            bf16x8 a = *(const bf16x8*)&At[mrow * AST + p * 8];
            bf16x8 b = wp[(s * 2 + wv) * 64 + lane];
            acc = __builtin_amdgcn_mfma_f32_16x16x32_bf16(a, b, acc, 0, 0, 0);
        }
        float bs = bias[wv * 16 + mrow];
#pragma unroll
        for (int r = 0; r < 4; ++r) {
            int v = (int)blockIdx.x * 16 + quad * 4 + r;
            out[(size_t)v * 32 + wv * 16 + mrow] = acc[r] + bs;
        }
    }
}

extern "C" void kernel_launch(void* const* d_in, const int* in_sizes, int n_in,
                              void* d_out, int out_size, void* d_ws, size_t ws_size,
                              hipStream_t stream) {
    const float* vox = (const float*)d_in[0];
    const float* verts = (const float*)d_in[1];
    const float* cw = (const float*)d_in[2];
    const float* cb = (const float*)d_in[3];
    float* out = (float*)d_out;

    // ws layout: Wp (64 KB) | voxT bf16 (2*HWD*32*2 = 113.25 MB). Total ~113.4 MB.
    unsigned short* Wp = (unsigned short*)d_ws;
    unsigned short* voxT = (unsigned short*)((char*)d_ws + 65536);

    hipLaunchKernelGGL(prep_kernel, dim3(128), dim3(256), 0, stream, cw, Wp);
    hipLaunchKernelGGL(transpose_kernel, dim3(18432), dim3(256), 0, stream, vox, voxT);
    hipLaunchKernelGGL(fused_kernel, dim3(3750), dim3(256), 0, stream,
                       voxT, verts, Wp, cb, out);
}

// Round 4
// 457.128 us; speedup vs baseline: 2.0146x; 2.0146x over previous
//
#include <hip/hip_runtime.h>
#include <stdint.h>

// Problem constants (fixed by setup_inputs): B=2, C=32, H=W=D=96, N=30000
#define HWD 884736ull          // 96*96*96
#define NV 30000               // vertices per batch
#define AST 1032               // LDS A-tile row stride (shorts); breaks pow2 strides

typedef __attribute__((ext_vector_type(8))) __bf16 bf16x8;
typedef __attribute__((ext_vector_type(4))) float f32x4;
typedef __attribute__((ext_vector_type(2))) unsigned int uint2v;
typedef __attribute__((ext_vector_type(4))) unsigned int uint4v;

__device__ __forceinline__ unsigned short f2bf(float f) {
    union { float f; unsigned int u; } v; v.f = f;
    unsigned int u = v.u;
    return (unsigned short)((u + 0x7FFFu + ((u >> 16) & 1u)) >> 16);  // RNE
}

__device__ __forceinline__ float bf_lo(unsigned int u) {
    union { unsigned int u; float f; } v; v.u = u << 16; return v.f;
}
__device__ __forceinline__ float bf_hi(unsigned int u) {
    union { unsigned int u; float f; } v; v.u = u & 0xffff0000u; return v.f;
}

// Per-axis: replicate reference clamp/floor math for shifts {-1,0,1}, then fold
// into 4-wide window weights. Window start ws = clamp(x0_center-1, 0, 92).
__device__ __forceinline__ void axis_setup(float coord, float sc, int& wstart, float w[3][4]) {
    int i0[3], i1[3];
    float fr[3];
#pragma unroll
    for (int a = 0; a < 3; ++a) {
        float g = coord + (float)(a - 1) * sc;
        float ix = (g + 1.0f) * 0.5f * 95.0f;
        ix = fminf(fmaxf(ix, 0.0f), 95.0f);
        float fl = floorf(ix);
        int x0 = (int)fl;
        i0[a] = x0;
        i1[a] = min(x0 + 1, 95);
        fr[a] = ix - fl;
    }
    int ws = min(max(i0[1] - 1, 0), 92);
    wstart = ws;
#pragma unroll
    for (int a = 0; a < 3; ++a) {
        int d0 = min(max(i0[a] - ws, 0), 3);
        int d1 = min(max(i1[a] - ws, 0), 3);
        float f1 = fr[a], f0 = 1.0f - f1;
#pragma unroll
        for (int j = 0; j < 4; ++j)
            w[a][j] = (d0 == j ? f0 : 0.0f) + (d1 == j ? f1 : 0.0f);
    }
}

// Pack conv_w (32,32,1,27) fp32 -> bf16 B-fragments for mfma_f32_16x16x32_bf16.
// element j of wp[(s*2+t)*64 + lane] is B[k = s*32 + (lane>>4)*8 + j][o = t*16 + (lane&15)]
__global__ __launch_bounds__(256) void prep_kernel(const float* __restrict__ cw,
                                                   unsigned short* __restrict__ Wp) {
    int gid = blockIdx.x * 256 + threadIdx.x;  // 0..32767
    int j = gid & 7;
    int l = (gid >> 3) & 63;
    int t = (gid >> 9) & 1;
    int s = gid >> 10;
    int kk = ((l >> 4) & 3) * 8 + j;
    int o = t * 16 + (l & 15);
    float v = 0.0f;
    if (kk < 27) v = cw[(size_t)o * 864 + s * 27 + kk];
    Wp[gid] = f2bf(v);
}

// (B,C,H,W,D) fp32 -> x-quad-packed bf16: voxQ[((b*9216+zy)*24 + q)*32 + c] is a
// uint2 holding taps x = 4q..4q+3 of channel c (2 bf16 per uint, low = even x).
// One block per (b,zy) row: reads float4 per lane, writes 8B per lane, 256B
// contiguous per 32-lane channel group.
__global__ __launch_bounds__(256) void transpose_kernel(const float* __restrict__ vox,
                                                        uint2v* __restrict__ voxQ) {
    int blk = blockIdx.x;            // 0..18431 encodes (b, zy)
    int tid = threadIdx.x;
    int b = blk / 9216;
    int zy = blk % 9216;
    const float* src = vox + (size_t)b * 32 * HWD + (size_t)zy * 96;
    uint2v* dst = voxQ + (size_t)blk * 768;
#pragma unroll
    for (int i = 0; i < 3; ++i) {
        int idx = i * 256 + tid;     // 0..767
        int c = idx & 31;
        int q = idx >> 5;            // 0..23
        f32x4 v = *(const f32x4*)(src + (size_t)c * HWD + q * 4);
        unsigned int u0 = (unsigned int)f2bf(v[0]) | ((unsigned int)f2bf(v[1]) << 16);
        unsigned int u1 = (unsigned int)f2bf(v[2]) | ((unsigned int)f2bf(v[3]) << 16);
        uint2v p = {u0, u1};
        dst[q * 32 + c] = p;
    }
}

// Fused sample + GEMM. Block = 512 threads = 16 vertices x 32 channels.
// Per thread: 16 (z,y) rows x 2 uint2 loads (quads q0, q0+1) cover the 4-tap
// x-window at runtime offset o = wsx&3 within 8 loaded taps; 7-wide x-weights
// built by static-index funnel shift. Separable x->y->z contraction to f[27],
// bf16-packed into the swizzled LDS A-tile; waves 0/1 run the MFMA GEMM.
__global__ __launch_bounds__(512) void fused_kernel(const uint2v* __restrict__ voxQ,
                                                    const float* __restrict__ verts,
                                                    const unsigned short* __restrict__ Wp,
                                                    const float* __restrict__ bias,
                                                    float* __restrict__ out) {
    __shared__ __align__(16) unsigned short At[16 * AST];
    int tid = threadIdx.x;
    int vl = tid >> 5;               // vertex-in-block 0..15
    int c = tid & 31;                // channel
    int vg = (int)blockIdx.x * 16 + vl;   // 3750*16 = 60000 exactly

    const float* vp = verts + (size_t)vg * 3;
    float vx = vp[0], vy = vp[1], vz = vp[2];
    const float sc = 2.0f / 95.0f;
    int wsx, wsy, wsz;
    float wx[3][4], wy[3][4], wz[3][4];
    axis_setup(vx, sc, wsx, wx);  // x -> D axis (innermost spatial)
    axis_setup(vy, sc, wsy, wy);  // y -> W axis
    axis_setup(vz, sc, wsz, wz);  // z -> H axis

    // 7-wide x-weights: wx7[a][o + j] = wx[a][j], o = wsx & 3 (static-index shifts)
    int o = wsx & 3;
    bool s1 = (o & 1) != 0, s2 = (o & 2) != 0;
    float wx7[3][7];
#pragma unroll
    for (int a = 0; a < 3; ++a) {
        float t0 = s1 ? 0.0f : wx[a][0];
        float t1 = s1 ? wx[a][0] : wx[a][1];
        float t2 = s1 ? wx[a][1] : wx[a][2];
        float t3 = s1 ? wx[a][2] : wx[a][3];
        float t4 = s1 ? wx[a][3] : 0.0f;
        wx7[a][0] = s2 ? 0.0f : t0;
        wx7[a][1] = s2 ? 0.0f : t1;
        wx7[a][2] = s2 ? t0 : t2;
        wx7[a][3] = s2 ? t1 : t3;
        wx7[a][4] = s2 ? t2 : t4;
        wx7[a][5] = s2 ? t3 : 0.0f;
        wx7[a][6] = s2 ? t4 : 0.0f;
    }
    int q0 = wsx >> 2;
    int q1 = min(q0 + 1, 23);        // clamp: when q0==23, o==0 so quad-2 weights are 0

    int bb = (vg >= NV) ? 1 : 0;
    const uint2v* Qb = voxQ + (size_t)bb * 9216 * 768 + c;

    float f[27];
#pragma unroll
    for (int k = 0; k < 27; ++k) f[k] = 0.0f;

#pragma unroll
    for (int tz = 0; tz < 4; ++tz) {
        float ry[9];
#pragma unroll
        for (int i = 0; i < 9; ++i) ry[i] = 0.0f;
#pragma unroll
        for (int ty = 0; ty < 4; ++ty) {
            size_t r = ((size_t)(wsz + tz) * 96 + (size_t)(wsy + ty)) * 24;
            uint2v A = Qb[(r + q0) * 32];
            uint2v Bq = Qb[(r + q1) * 32];
            float b0 = bf_lo(A[0]), b1 = bf_hi(A[0]), b2 = bf_lo(A[1]), b3 = bf_hi(A[1]);
            float b4 = bf_lo(Bq[0]), b5 = bf_hi(Bq[0]), b6 = bf_lo(Bq[1]);
#pragma unroll
            for (int a = 0; a < 3; ++a) {
                float rxt = b0 * wx7[a][0] + b1 * wx7[a][1] + b2 * wx7[a][2] +
                            b3 * wx7[a][3] + b4 * wx7[a][4] + b5 * wx7[a][5] +
                            b6 * wx7[a][6];
#pragma unroll
                for (int b = 0; b < 3; ++b)
                    ry[3 * b + a] = fmaf(rxt, wy[b][ty], ry[3 * b + a]);
            }
        }
#pragma unroll
        for (int g = 0; g < 3; ++g)
#pragma unroll
            for (int b = 0; b < 3; ++b)
#pragma unroll
                for (int a = 0; a < 3; ++a)
                    f[9 * a + 3 * b + g] = fmaf(ry[3 * b + a], wz[g][tz], f[9 * a + 3 * b + g]);
    }

    // Pack 27+5pad taps into 4 16B units; unit j stored at rotate-swizzled slot
    // c*4 + ((j + c) & 3) to spread LDS write bank groups.
    unsigned short* rowp = &At[vl * AST];
#pragma unroll
    for (int j = 0; j < 4; ++j) {
        const int kb = j * 8;
        unsigned int pw[4];
#pragma unroll
        for (int t2 = 0; t2 < 4; ++t2) {
            int k0 = kb + 2 * t2, k1 = k0 + 1;
            float lo = (k0 < 27) ? f[k0] : 0.0f;
            float hi = (k1 < 27) ? f[k1] : 0.0f;
            pw[t2] = (unsigned int)f2bf(lo) | ((unsigned int)f2bf(hi) << 16);
        }
        uint4v s = {pw[0], pw[1], pw[2], pw[3]};
        int p = c * 4 + ((j + c) & 3);
        *(uint4v*)(rowp + p * 8) = s;
    }

    __syncthreads();

    int wv = tid >> 6;               // wave id 0..7; waves 0,1 do the GEMM
    if (wv < 2) {
        int lane = tid & 63;
        int mrow = lane & 15, quad = lane >> 4;
        const bf16x8* wp = (const bf16x8*)Wp;
        f32x4 acc = {0.f, 0.f, 0.f, 0.f};
#pragma unroll 8
        for (int s = 0; s < 32; ++s) {
            int p = s * 4 + ((quad + s) & 3);     // un-swizzle (c=s, j=quad)
            bf16x8 a = *(const bf16x8*)&At[mrow * AST + p * 8];
            bf16x8 b = wp[(s * 2 + wv) * 64 + lane];
            acc = __builtin_amdgcn_mfma_f32_16x16x32_bf16(a, b, acc, 0, 0, 0);
        }
        float bs = bias[wv * 16 + mrow];
#pragma unroll
        for (int r = 0; r < 4; ++r) {
            int v = (int)blockIdx.x * 16 + quad * 4 + r;
            out[(size_t)v * 32 + wv * 16 + mrow] = acc[r] + bs;
        }
    }
}

extern "C" void kernel_launch(void* const* d_in, const int* in_sizes, int n_in,
                              void* d_out, int out_size, void* d_ws, size_t ws_size,
                              hipStream_t stream) {
    const float* vox = (const float*)d_in[0];
    const float* verts = (const float*)d_in[1];
    const float* cw = (const float*)d_in[2];
    const float* cb = (const float*)d_in[3];
    float* out = (float*)d_out;

    // ws layout: Wp (64 KB) | voxQ bf16 quad-packed (2*HWD*32*2 = 113.25 MB).
    unsigned short* Wp = (unsigned short*)d_ws;
    uint2v* voxQ = (uint2v*)((char*)d_ws + 65536);

    hipLaunchKernelGGL(prep_kernel, dim3(128), dim3(256), 0, stream, cw, Wp);
    hipLaunchKernelGGL(transpose_kernel, dim3(18432), dim3(256), 0, stream, vox, voxQ);
    hipLaunchKernelGGL(fused_kernel, dim3(3750), dim3(512), 0, stream,
                       voxQ, verts, Wp, cb, out);
}